// Round 1
// baseline (527.644 us; speedup 1.0000x reference)
//
#include <hip/hip_runtime.h>
#include <hip/hip_fp16.h>
#include <math.h>

#define HID 64
#define CBITS 6
#define CSZ 64           // nodes per bucket
#define MAXB 2048        // max buckets supported (N <= 131072)
#define CAP 832          // record slots per bucket (mean 640, sigma ~25 -> +7.6 sigma)
#define PB 896           // proj blocks in the fused mid kernel
#define MSB 256          // multisplit blocks in the fused mid kernel

// ---- float4 helpers -------------------------------------------------------
__device__ __forceinline__ float4 f4fma(float a, const float4 b, float4 c) {
    c.x = fmaf(a, b.x, c.x); c.y = fmaf(a, b.y, c.y);
    c.z = fmaf(a, b.z, c.z); c.w = fmaf(a, b.w, c.w);
    return c;
}

// block 0: vdst[k] = sum_h W_dst[k][h]*att_dst[h]; all blocks: gcursor[i] = i*CAP.
__global__ void init_kernel(const float* __restrict__ W_dst,
                            const float* __restrict__ att_dst,
                            float* __restrict__ vdst,
                            int* __restrict__ gcursor, int nbc) {
    if (blockIdx.x == 0 && threadIdx.x < HID) {
        int k = threadIdx.x;
        float acc = 0.0f;
#pragma unroll 8
        for (int h = 0; h < HID; ++h) acc = fmaf(W_dst[k * HID + h], att_dst[h], acc);
        vdst[k] = acc;
    }
    int stride = gridDim.x * blockDim.x;
    for (int i = blockIdx.x * blockDim.x + threadIdx.x; i < nbc; i += stride)
        gcursor[i] = i * CAP;
}

// Fused mid kernel: blocks [0,PB) run the projection, blocks [PB,PB+MSB) run the
// multisplit. The two phases are data-independent; fusing them lets them overlap
// on the device (both are latency-bound and individually underutilize it).
// LDS is a union (25 KB) -> 6 blocks/CU, 1152 blocks all co-resident.
//
// proj: h_half = fp16(x @ W_src) in PERMUTED feature order; a_src; a_dst.
//   FEATURE PERMUTATION: W_src/att_src are staged into LDS so that lane s
//   computes features {s, s+16, s+32, s+48} (instead of {4s..4s+3}). The packed
//   h row therefore stores feature s+16*i at half-position 4s+i. The gather
//   kernel's ds_add_f32 accumulation then hits LDS addresses tl*64 + s + 16*i:
//   16 consecutive banks per instruction (4-way conflict max) instead of the
//   8-bank / 8-way pattern a stride-4 layout would give. The dot-product
//   reductions (a_src) are permutation-invariant; a_dst (input-dim dot) is
//   untouched; lacc ends up in NATURAL feature order so the output GEMM and
//   bias/W_lin indexing are unchanged.
//   K-loop unrolled only 4x: full unroll makes the compiler hoist 64 loop-
//   invariant LDS float4 loads -> spill to scratch -> ~950 MB phantom HBM
//   traffic (R3/R4 lesson).
// multisplit: bucket i owns rec[i*CAP,(i+1)*CAP). LDS hist -> one global-atomic
//   reservation per bucket per block -> LDS-cursor placement. Record =
//   (src<<6)|(tgt&63). Same-block writes are contiguous ~20 B runs -> no 16x
//   random write-back amplification (R6 lesson).
__global__ void __launch_bounds__(256)
mid_kernel(const float* __restrict__ x,
           const float* __restrict__ W_src,
           const float* __restrict__ att_src,
           const float* __restrict__ vdst,
           __half* __restrict__ h_half,
           float* __restrict__ a_src,
           float* __restrict__ a_dst, int N,
           const int* __restrict__ src, const int* __restrict__ tgt,
           int* __restrict__ gcursor, int* __restrict__ rec, int E, int nbc) {
    __shared__ __align__(16) char smraw[25088];
    const int t = threadIdx.x;

    if (blockIdx.x < PB) {
        // ---------------- projection ----------------
        float4* Ws4  = (float4*)smraw;        // [HID*16]
        float4* att4 = Ws4 + HID * 16;        // [16]
        float4* vd4  = att4 + 16;             // [16]
        float*  xs   = (float*)(vd4 + 16);    // [32*HID]

        // permuted staging: element (k,s) = {W[k][s], W[k][s+16], W[k][s+32], W[k][s+48]}
        for (int i = t; i < HID * 16; i += 256) {
            int k = i >> 4, sc = i & 15;
            const float* wr = W_src + k * HID + sc;
            Ws4[i] = make_float4(wr[0], wr[16], wr[32], wr[48]);
        }
        if (t < 16) {
            att4[t] = make_float4(att_src[t], att_src[t + 16],
                                  att_src[t + 32], att_src[t + 48]);
            vd4[t]  = ((const float4*)vdst)[t];
        }

        const int g0 = t >> 4;       // node slot 0..15 (second node = g0+16)
        const int s = t & 15;        // float4 chunk within the 64-wide feature dim
        const float4* x4 = (const float4*)x;
        uint2* h2 = (uint2*)h_half;
        float4* xs4 = (float4*)xs;

        for (int base = blockIdx.x * 32; base < N; base += PB * 32) {
            __syncthreads();  // also covers the Ws4 fill on iteration 0
#pragma unroll
            for (int u = 0; u < 2; ++u) {
                int f = t + u * 256;                 // flat float4 id 0..511
                int node = base + (f >> 4);
                xs4[f] = (node < N) ? x4[(long long)node * 16 + (f & 15)]
                                    : make_float4(0, 0, 0, 0);
            }
            __syncthreads();

            const float* xr0 = xs + g0 * HID;
            const float* xr1 = xs + (g0 + 16) * HID;

            float4 acc0 = make_float4(0, 0, 0, 0);
            float4 acc1 = make_float4(0, 0, 0, 0);
#pragma unroll 4
            for (int k = 0; k < HID; ++k) {
                float4 w = Ws4[k * 16 + s];
                acc0 = f4fma(xr0[k], w, acc0);
                acc1 = f4fma(xr1[k], w, acc1);
            }

            float4 av = att4[s], qv = vd4[s];
            float p0 = acc0.x * av.x + acc0.y * av.y + acc0.z * av.z + acc0.w * av.w;
            float p1 = acc1.x * av.x + acc1.y * av.y + acc1.z * av.z + acc1.w * av.w;
            float q0 = xr0[4 * s] * qv.x + xr0[4 * s + 1] * qv.y +
                       xr0[4 * s + 2] * qv.z + xr0[4 * s + 3] * qv.w;
            float q1 = xr1[4 * s] * qv.x + xr1[4 * s + 1] * qv.y +
                       xr1[4 * s + 2] * qv.z + xr1[4 * s + 3] * qv.w;
#pragma unroll
            for (int off = 1; off < 16; off <<= 1) {
                p0 += __shfl_xor(p0, off, 64);
                p1 += __shfl_xor(p1, off, 64);
                q0 += __shfl_xor(q0, off, 64);
                q1 += __shfl_xor(q1, off, 64);
            }

            int n0 = base + g0, n1 = base + g0 + 16;
            if (n0 < N) {
                __half2 lo = __float22half2_rn(make_float2(acc0.x, acc0.y));
                __half2 hi = __float22half2_rn(make_float2(acc0.z, acc0.w));
                uint2 pk; pk.x = *(unsigned*)&lo; pk.y = *(unsigned*)&hi;
                h2[(long long)n0 * 16 + s] = pk;
                if (s == 0) { a_src[n0] = p0; a_dst[n0] = q0; }
            }
            if (n1 < N) {
                __half2 lo = __float22half2_rn(make_float2(acc1.x, acc1.y));
                __half2 hi = __float22half2_rn(make_float2(acc1.z, acc1.w));
                uint2 pk; pk.x = *(unsigned*)&lo; pk.y = *(unsigned*)&hi;
                h2[(long long)n1 * 16 + s] = pk;
                if (s == 0) { a_src[n1] = p1; a_dst[n1] = q1; }
            }
        }
    } else {
        // ---------------- multisplit ----------------
        int* lh = (int*)smraw;                // [nbc]
        const int bid = blockIdx.x - PB;

        for (int i = t; i < nbc; i += 256) lh[i] = 0;
        __syncthreads();
        int chunk = (E + MSB - 1) / MSB;
        int e0 = bid * chunk;
        int e1 = min(E, e0 + chunk);
        for (int e = e0 + t; e < e1; e += 256)
            atomicAdd(&lh[tgt[e] >> CBITS], 1);
        __syncthreads();
        // reserve: lh[i] becomes this block's base slot for bucket i
        for (int i = t; i < nbc; i += 256)
            if (lh[i]) lh[i] = atomicAdd(&gcursor[i], lh[i]);
        __syncthreads();
        for (int e = e0 + t; e < e1; e += 256) {
            int s = src[e], tg = tgt[e];
            int bi = tg >> CBITS;
            int pos = atomicAdd(&lh[bi], 1);           // LDS atomic (~50cy, not ~500)
            if (pos < (bi + 1) * CAP)                  // overflow guard
                rec[pos] = (s << CBITS) | (tg & (CSZ - 1));
        }
    }
}

// Sort-free gather: ONE 512-thread block per 64-node bucket. Records are read
// once (int4-vectorized, 16-lane-group per record, unroll 4) and accumulated
// directly into per-target LDS accumulators via fire-and-forget ds_add_f32 --
// no counting sort, no second rec pass, no per-node trip-count divergence.
// Thanks to the permuted h layout, lane s's four adds hit lacc[tl*64+s+16i]:
// 16 consecutive banks per instruction (4-way conflict max across the wave's
// 4 groups). lacc is in NATURAL feature order, so the epilogue
// (acc/dsum+bias)@W_lin+relu is identical to before.
// LDS = 16K (W_lin) + 16K (lacc) + ~1K = ~33.4 KB -> 4 blocks/CU x 512 thr
// = 2048 threads/CU = 100% occupancy (launch_bounds caps VGPR at 64).
__global__ void __launch_bounds__(512, 8)
gather_kernel(const int* __restrict__ gcursor, const int* __restrict__ rec,
              const __half* __restrict__ h_half,
              const float* __restrict__ a_src, const float* __restrict__ a_dst,
              const float* __restrict__ bias,
              const float* __restrict__ W_lin, const float* __restrict__ b_lin,
              float* __restrict__ out, int N) {
    __shared__ float4 Wl4[HID * 16];                 // 16 KB
    __shared__ float4 bs4[16], bl4[16];
    __shared__ __align__(16) float lacc[CSZ * HID];  // 16 KB, natural feature order
    __shared__ float ldsum[CSZ];
    __shared__ float ladst[CSZ];

    const int t = threadIdx.x;
    for (int i = t; i < HID * 16; i += 512) Wl4[i] = ((const float4*)W_lin)[i];
    if (t < 16) {
        bs4[t] = ((const float4*)bias)[t];
        bl4[t] = ((const float4*)b_lin)[t];
    }
    const int bk = blockIdx.x;
    const int node0 = bk << CBITS;
    for (int i = t; i < CSZ * HID; i += 512) lacc[i] = 0.0f;
    if (t < CSZ) {
        int n = node0 + t;
        ldsum[t] = 0.0f;
        ladst[t] = (n < N) ? a_dst[n] : 0.0f;
    }
    const int beg = bk * CAP;
    int cnt = gcursor[bk] - beg;
    if (cnt > CAP) cnt = CAP;
    __syncthreads();

    const int gid = t >> 4;      // record-group 0..31
    const int s = t & 15;        // feature chunk within group
    const uint2* h2 = (const uint2*)h_half;

    // per-group contiguous chunk, rounded to 4 so int4 loads stay 16B-aligned
    int chunk = ((cnt + 31) >> 5 + 0);
    chunk = (chunk + 3) & ~3;
    int j0 = gid * chunk;
    int j1 = min(cnt, j0 + chunk);
    int j = j0;
#pragma unroll 1
    for (; j + 4 <= j1; j += 4) {
        int4 rr = *(const int4*)(rec + beg + j);     // 16B broadcast within group
        int sa = rr.x >> CBITS, ta = rr.x & (CSZ - 1);
        int sb = rr.y >> CBITS, tb = rr.y & (CSZ - 1);
        int sc = rr.z >> CBITS, tc = rr.z & (CSZ - 1);
        int sd = rr.w >> CBITS, td = rr.w & (CSZ - 1);
        uint2 r0 = h2[(long long)sa * 16 + s];
        uint2 r1 = h2[(long long)sb * 16 + s];
        uint2 r2 = h2[(long long)sc * 16 + s];
        uint2 r3 = h2[(long long)sd * 16 + s];
        float v0 = a_src[sa] + ladst[ta];
        float v1 = a_src[sb] + ladst[tb];
        float v2 = a_src[sc] + ladst[tc];
        float v3 = a_src[sd] + ladst[td];
        v0 = (v0 > 0.0f) ? v0 : 0.2f * v0;
        v1 = (v1 > 0.0f) ? v1 : 0.2f * v1;
        v2 = (v2 > 0.0f) ? v2 : 0.2f * v2;
        v3 = (v3 > 0.0f) ? v3 : 0.2f * v3;
        float w0 = __expf(v0), w1 = __expf(v1);
        float w2 = __expf(v2), w3 = __expf(v3);
        float2 f0a = __half22float2(*(const __half2*)&r0.x);
        float2 f0b = __half22float2(*(const __half2*)&r0.y);
        float2 f1a = __half22float2(*(const __half2*)&r1.x);
        float2 f1b = __half22float2(*(const __half2*)&r1.y);
        float2 f2a = __half22float2(*(const __half2*)&r2.x);
        float2 f2b = __half22float2(*(const __half2*)&r2.y);
        float2 f3a = __half22float2(*(const __half2*)&r3.x);
        float2 f3b = __half22float2(*(const __half2*)&r3.y);
        float* p0 = lacc + ta * HID + s;
        float* p1 = lacc + tb * HID + s;
        float* p2 = lacc + tc * HID + s;
        float* p3 = lacc + td * HID + s;
        atomicAdd(p0 +  0, w0 * f0a.x);
        atomicAdd(p0 + 16, w0 * f0a.y);
        atomicAdd(p0 + 32, w0 * f0b.x);
        atomicAdd(p0 + 48, w0 * f0b.y);
        atomicAdd(p1 +  0, w1 * f1a.x);
        atomicAdd(p1 + 16, w1 * f1a.y);
        atomicAdd(p1 + 32, w1 * f1b.x);
        atomicAdd(p1 + 48, w1 * f1b.y);
        atomicAdd(p2 +  0, w2 * f2a.x);
        atomicAdd(p2 + 16, w2 * f2a.y);
        atomicAdd(p2 + 32, w2 * f2b.x);
        atomicAdd(p2 + 48, w2 * f2b.y);
        atomicAdd(p3 +  0, w3 * f3a.x);
        atomicAdd(p3 + 16, w3 * f3a.y);
        atomicAdd(p3 + 32, w3 * f3b.x);
        atomicAdd(p3 + 48, w3 * f3b.y);
        if (s == 0) {
            atomicAdd(&ldsum[ta], w0);
            atomicAdd(&ldsum[tb], w1);
            atomicAdd(&ldsum[tc], w2);
            atomicAdd(&ldsum[td], w3);
        }
    }
#pragma unroll 1
    for (; j < j1; ++j) {
        int r = rec[beg + j];
        int sa = r >> CBITS, ta = r & (CSZ - 1);
        uint2 r0 = h2[(long long)sa * 16 + s];
        float v0 = a_src[sa] + ladst[ta];
        v0 = (v0 > 0.0f) ? v0 : 0.2f * v0;
        float w0 = __expf(v0);
        float2 f0a = __half22float2(*(const __half2*)&r0.x);
        float2 f0b = __half22float2(*(const __half2*)&r0.y);
        float* p0 = lacc + ta * HID + s;
        atomicAdd(p0 +  0, w0 * f0a.x);
        atomicAdd(p0 + 16, w0 * f0a.y);
        atomicAdd(p0 + 32, w0 * f0b.x);
        atomicAdd(p0 + 48, w0 * f0b.y);
        if (s == 0) atomicAdd(&ldsum[ta], w0);
    }
    __syncthreads();

    // ---- epilogue: out = relu((acc/dsum + bias) @ W_lin + b_lin) ----
    const int lane = t & 63;
    const int gbase = (lane >> 4) << 4;
    float4* out4 = (float4*)out;
#pragma unroll 1
    for (int rnd = 0; rnd < 2; ++rnd) {
        int nloc = rnd * 32 + gid;
        int n = node0 + nloc;
        float4 acc = *(const float4*)(lacc + nloc * HID + 4 * s);
        float inv = 1.0f / (ldsum[nloc] + 1e-16f);
        float4 bsv = bs4[s];
        float4 r;
        r.x = fmaf(acc.x, inv, bsv.x);
        r.y = fmaf(acc.y, inv, bsv.y);
        r.z = fmaf(acc.z, inv, bsv.z);
        r.w = fmaf(acc.w, inv, bsv.w);

        float4 o = bl4[s];
#pragma unroll 4
        for (int ks = 0; ks < 16; ++ks) {
            float rx = __shfl(r.x, gbase + ks, 64);
            float ry = __shfl(r.y, gbase + ks, 64);
            float rz = __shfl(r.z, gbase + ks, 64);
            float rw = __shfl(r.w, gbase + ks, 64);
            o = f4fma(rx, Wl4[(4 * ks + 0) * 16 + s], o);
            o = f4fma(ry, Wl4[(4 * ks + 1) * 16 + s], o);
            o = f4fma(rz, Wl4[(4 * ks + 2) * 16 + s], o);
            o = f4fma(rw, Wl4[(4 * ks + 3) * 16 + s], o);
        }

        if (n < N) {
            float4 res;
            res.x = o.x > 0.0f ? o.x : 0.0f;
            res.y = o.y > 0.0f ? o.y : 0.0f;
            res.z = o.z > 0.0f ? o.z : 0.0f;
            res.w = o.w > 0.0f ? o.w : 0.0f;
            out4[(long long)n * 16 + s] = res;
        }
    }
}

extern "C" void kernel_launch(void* const* d_in, const int* in_sizes, int n_in,
                              void* d_out, int out_size, void* d_ws, size_t ws_size,
                              hipStream_t stream) {
    const float* x       = (const float*)d_in[0];
    const int*   edge    = (const int*)d_in[1];
    const float* W_src   = (const float*)d_in[2];
    const float* W_dst   = (const float*)d_in[3];
    const float* att_src = (const float*)d_in[4];
    const float* att_dst = (const float*)d_in[5];
    const float* bias    = (const float*)d_in[6];
    const float* W_lin   = (const float*)d_in[7];
    const float* b_lin   = (const float*)d_in[8];
    float* out = (float*)d_out;

    const int N = in_sizes[0] / HID;  // 100000
    const int E = in_sizes[1] / 2;    // 1000000
    const int* src = edge;
    const int* tgt = edge + E;
    const int nbc = (N + CSZ - 1) / CSZ;   // 1563 buckets

    // workspace layout
    __half* h_half  = (__half*)d_ws;                      // N*HID halves
    float*  a_src   = (float*)(h_half + (size_t)N * HID); // N
    float*  a_dst   = a_src + N;                          // N
    float*  vdst    = a_dst + N;                          // 64
    int*    gcursor = (int*)(vdst + 64);                  // MAXB
    int*    rec     = gcursor + MAXB;                     // nbc*CAP (~5.2 MB)

    init_kernel<<<8, 256, 0, stream>>>(W_dst, att_dst, vdst, gcursor, nbc);
    mid_kernel<<<PB + MSB, 256, 0, stream>>>(x, W_src, att_src, vdst, h_half,
                                             a_src, a_dst, N,
                                             src, tgt, gcursor, rec, E, nbc);
    gather_kernel<<<nbc, 512, 0, stream>>>(gcursor, rec, h_half, a_src, a_dst,
                                           bias, W_lin, b_lin, out, N);
}

// Round 2
// 525.539 us; speedup vs baseline: 1.0040x; 1.0040x over previous
//
#include <hip/hip_runtime.h>
#include <hip/hip_fp16.h>
#include <math.h>

#define HID 64
#define CBITS 6
#define CSZ 64           // nodes per bucket
#define MAXB 2048        // max buckets supported (N <= 131072)
#define CAP 832          // record slots per bucket (mean 640, sigma ~25 -> +7.6 sigma)
#define PB 896           // proj blocks in the fused mid kernel
#define MSB 256          // multisplit blocks in the fused mid kernel

// ---- float4 helpers -------------------------------------------------------
__device__ __forceinline__ float4 f4fma(float a, const float4 b, float4 c) {
    c.x = fmaf(a, b.x, c.x); c.y = fmaf(a, b.y, c.y);
    c.z = fmaf(a, b.z, c.z); c.w = fmaf(a, b.w, c.w);
    return c;
}

// LDS float add that is guaranteed to lower to hardware ds_add_f32 (no-return).
// Plain atomicAdd(float*) under the default safe-FP policy expands to a
// ds_read/ds_cmpst CAS loop (~2 dependent LDS round-trips per add) -> the R1
// 8x regression (VALUBusy 4%, bank conflicts ~0 because ds_add never ran).
__device__ __forceinline__ void lds_fadd(float* p, float v) {
    unsafeAtomicAdd(p, v);
}

// block 0: vdst[k] = sum_h W_dst[k][h]*att_dst[h]; all blocks: gcursor[i] = i*CAP.
__global__ void init_kernel(const float* __restrict__ W_dst,
                            const float* __restrict__ att_dst,
                            float* __restrict__ vdst,
                            int* __restrict__ gcursor, int nbc) {
    if (blockIdx.x == 0 && threadIdx.x < HID) {
        int k = threadIdx.x;
        float acc = 0.0f;
#pragma unroll 8
        for (int h = 0; h < HID; ++h) acc = fmaf(W_dst[k * HID + h], att_dst[h], acc);
        vdst[k] = acc;
    }
    int stride = gridDim.x * blockDim.x;
    for (int i = blockIdx.x * blockDim.x + threadIdx.x; i < nbc; i += stride)
        gcursor[i] = i * CAP;
}

// Fused mid kernel: blocks [0,PB) run the projection, blocks [PB,PB+MSB) run the
// multisplit. The two phases are data-independent; fusing them lets them overlap
// on the device (both are latency-bound and individually underutilize it).
// LDS is a union (25 KB) -> 6 blocks/CU, 1152 blocks all co-resident.
//
// proj: h_half = fp16(x @ W_src) in PERMUTED feature order; a_src; a_dst.
//   FEATURE PERMUTATION: W_src/att_src are staged into LDS so that lane s
//   computes features {s, s+16, s+32, s+48} (instead of {4s..4s+3}). The packed
//   h row therefore stores feature s+16*i at half-position 4s+i. The gather
//   kernel's ds_add_f32 accumulation then hits LDS addresses tl*64 + s + 16*i:
//   16 consecutive banks per instruction (4-way conflict max) instead of the
//   8-bank / 8-way pattern a stride-4 layout would give. The dot-product
//   reductions (a_src) are permutation-invariant; a_dst (input-dim dot) is
//   untouched; lacc ends up in NATURAL feature order so the output GEMM and
//   bias/W_lin indexing are unchanged.
//   K-loop unrolled only 4x: full unroll makes the compiler hoist 64 loop-
//   invariant LDS float4 loads -> spill to scratch -> ~950 MB phantom HBM
//   traffic (R3/R4 lesson).
// multisplit: bucket i owns rec[i*CAP,(i+1)*CAP). LDS hist -> one global-atomic
//   reservation per bucket per block -> LDS-cursor placement. Record =
//   (src<<6)|(tgt&63). Same-block writes are contiguous ~20 B runs -> no 16x
//   random write-back amplification (R6 lesson).
__global__ void __launch_bounds__(256)
mid_kernel(const float* __restrict__ x,
           const float* __restrict__ W_src,
           const float* __restrict__ att_src,
           const float* __restrict__ vdst,
           __half* __restrict__ h_half,
           float* __restrict__ a_src,
           float* __restrict__ a_dst, int N,
           const int* __restrict__ src, const int* __restrict__ tgt,
           int* __restrict__ gcursor, int* __restrict__ rec, int E, int nbc) {
    __shared__ __align__(16) char smraw[25088];
    const int t = threadIdx.x;

    if (blockIdx.x < PB) {
        // ---------------- projection ----------------
        float4* Ws4  = (float4*)smraw;        // [HID*16]
        float4* att4 = Ws4 + HID * 16;        // [16]
        float4* vd4  = att4 + 16;             // [16]
        float*  xs   = (float*)(vd4 + 16);    // [32*HID]

        // permuted staging: element (k,s) = {W[k][s], W[k][s+16], W[k][s+32], W[k][s+48]}
        for (int i = t; i < HID * 16; i += 256) {
            int k = i >> 4, sc = i & 15;
            const float* wr = W_src + k * HID + sc;
            Ws4[i] = make_float4(wr[0], wr[16], wr[32], wr[48]);
        }
        if (t < 16) {
            att4[t] = make_float4(att_src[t], att_src[t + 16],
                                  att_src[t + 32], att_src[t + 48]);
            vd4[t]  = ((const float4*)vdst)[t];
        }

        const int g0 = t >> 4;       // node slot 0..15 (second node = g0+16)
        const int s = t & 15;        // float4 chunk within the 64-wide feature dim
        const float4* x4 = (const float4*)x;
        uint2* h2 = (uint2*)h_half;
        float4* xs4 = (float4*)xs;

        for (int base = blockIdx.x * 32; base < N; base += PB * 32) {
            __syncthreads();  // also covers the Ws4 fill on iteration 0
#pragma unroll
            for (int u = 0; u < 2; ++u) {
                int f = t + u * 256;                 // flat float4 id 0..511
                int node = base + (f >> 4);
                xs4[f] = (node < N) ? x4[(long long)node * 16 + (f & 15)]
                                    : make_float4(0, 0, 0, 0);
            }
            __syncthreads();

            const float* xr0 = xs + g0 * HID;
            const float* xr1 = xs + (g0 + 16) * HID;

            float4 acc0 = make_float4(0, 0, 0, 0);
            float4 acc1 = make_float4(0, 0, 0, 0);
#pragma unroll 4
            for (int k = 0; k < HID; ++k) {
                float4 w = Ws4[k * 16 + s];
                acc0 = f4fma(xr0[k], w, acc0);
                acc1 = f4fma(xr1[k], w, acc1);
            }

            float4 av = att4[s], qv = vd4[s];
            float p0 = acc0.x * av.x + acc0.y * av.y + acc0.z * av.z + acc0.w * av.w;
            float p1 = acc1.x * av.x + acc1.y * av.y + acc1.z * av.z + acc1.w * av.w;
            float q0 = xr0[4 * s] * qv.x + xr0[4 * s + 1] * qv.y +
                       xr0[4 * s + 2] * qv.z + xr0[4 * s + 3] * qv.w;
            float q1 = xr1[4 * s] * qv.x + xr1[4 * s + 1] * qv.y +
                       xr1[4 * s + 2] * qv.z + xr1[4 * s + 3] * qv.w;
#pragma unroll
            for (int off = 1; off < 16; off <<= 1) {
                p0 += __shfl_xor(p0, off, 64);
                p1 += __shfl_xor(p1, off, 64);
                q0 += __shfl_xor(q0, off, 64);
                q1 += __shfl_xor(q1, off, 64);
            }

            int n0 = base + g0, n1 = base + g0 + 16;
            if (n0 < N) {
                __half2 lo = __float22half2_rn(make_float2(acc0.x, acc0.y));
                __half2 hi = __float22half2_rn(make_float2(acc0.z, acc0.w));
                uint2 pk; pk.x = *(unsigned*)&lo; pk.y = *(unsigned*)&hi;
                h2[(long long)n0 * 16 + s] = pk;
                if (s == 0) { a_src[n0] = p0; a_dst[n0] = q0; }
            }
            if (n1 < N) {
                __half2 lo = __float22half2_rn(make_float2(acc1.x, acc1.y));
                __half2 hi = __float22half2_rn(make_float2(acc1.z, acc1.w));
                uint2 pk; pk.x = *(unsigned*)&lo; pk.y = *(unsigned*)&hi;
                h2[(long long)n1 * 16 + s] = pk;
                if (s == 0) { a_src[n1] = p1; a_dst[n1] = q1; }
            }
        }
    } else {
        // ---------------- multisplit ----------------
        int* lh = (int*)smraw;                // [nbc]
        const int bid = blockIdx.x - PB;

        for (int i = t; i < nbc; i += 256) lh[i] = 0;
        __syncthreads();
        int chunk = (E + MSB - 1) / MSB;
        int e0 = bid * chunk;
        int e1 = min(E, e0 + chunk);
        for (int e = e0 + t; e < e1; e += 256)
            atomicAdd(&lh[tgt[e] >> CBITS], 1);
        __syncthreads();
        // reserve: lh[i] becomes this block's base slot for bucket i
        for (int i = t; i < nbc; i += 256)
            if (lh[i]) lh[i] = atomicAdd(&gcursor[i], lh[i]);
        __syncthreads();
        for (int e = e0 + t; e < e1; e += 256) {
            int s = src[e], tg = tgt[e];
            int bi = tg >> CBITS;
            int pos = atomicAdd(&lh[bi], 1);           // LDS atomic (~50cy, not ~500)
            if (pos < (bi + 1) * CAP)                  // overflow guard
                rec[pos] = (s << CBITS) | (tg & (CSZ - 1));
        }
    }
}

// Sort-free gather: ONE 512-thread block per 64-node bucket. Records are read
// once (int4-vectorized, 16-lane-group per record, unroll 4) and accumulated
// directly into per-target LDS accumulators via fire-and-forget ds_add_f32
// (unsafeAtomicAdd -- see lds_fadd) -- no counting sort, no second rec pass,
// no per-node trip-count divergence.
// Thanks to the permuted h layout, lane s's four adds hit lacc[tl*64+s+16i]:
// 16 consecutive banks per instruction (4-way conflict max across the wave's
// 4 groups). lacc is in NATURAL feature order, so the epilogue
// (acc/dsum+bias)@W_lin+relu is identical to before.
// LDS = 16K (W_lin) + 16K (lacc) + ~1K = ~33.4 KB -> 4 blocks/CU x 512 thr
// = 2048 threads/CU = 100% occupancy (launch_bounds caps VGPR at 64).
__global__ void __launch_bounds__(512, 8)
gather_kernel(const int* __restrict__ gcursor, const int* __restrict__ rec,
              const __half* __restrict__ h_half,
              const float* __restrict__ a_src, const float* __restrict__ a_dst,
              const float* __restrict__ bias,
              const float* __restrict__ W_lin, const float* __restrict__ b_lin,
              float* __restrict__ out, int N) {
    __shared__ float4 Wl4[HID * 16];                 // 16 KB
    __shared__ float4 bs4[16], bl4[16];
    __shared__ __align__(16) float lacc[CSZ * HID];  // 16 KB, natural feature order
    __shared__ float ldsum[CSZ];
    __shared__ float ladst[CSZ];

    const int t = threadIdx.x;
    for (int i = t; i < HID * 16; i += 512) Wl4[i] = ((const float4*)W_lin)[i];
    if (t < 16) {
        bs4[t] = ((const float4*)bias)[t];
        bl4[t] = ((const float4*)b_lin)[t];
    }
    const int bk = blockIdx.x;
    const int node0 = bk << CBITS;
    for (int i = t; i < CSZ * HID; i += 512) lacc[i] = 0.0f;
    if (t < CSZ) {
        int n = node0 + t;
        ldsum[t] = 0.0f;
        ladst[t] = (n < N) ? a_dst[n] : 0.0f;
    }
    const int beg = bk * CAP;
    int cnt = gcursor[bk] - beg;
    if (cnt > CAP) cnt = CAP;
    __syncthreads();

    const int gid = t >> 4;      // record-group 0..31
    const int s = t & 15;        // feature chunk within group
    const uint2* h2 = (const uint2*)h_half;

    // per-group contiguous chunk, rounded to 4 so int4 loads stay 16B-aligned
    int chunk = (cnt + 31) >> 5;
    chunk = (chunk + 3) & ~3;
    int j0 = gid * chunk;
    int j1 = min(cnt, j0 + chunk);
    int j = j0;
#pragma unroll 1
    for (; j + 4 <= j1; j += 4) {
        int4 rr = *(const int4*)(rec + beg + j);     // 16B broadcast within group
        int sa = rr.x >> CBITS, ta = rr.x & (CSZ - 1);
        int sb = rr.y >> CBITS, tb = rr.y & (CSZ - 1);
        int sc = rr.z >> CBITS, tc = rr.z & (CSZ - 1);
        int sd = rr.w >> CBITS, td = rr.w & (CSZ - 1);
        uint2 r0 = h2[(long long)sa * 16 + s];
        uint2 r1 = h2[(long long)sb * 16 + s];
        uint2 r2 = h2[(long long)sc * 16 + s];
        uint2 r3 = h2[(long long)sd * 16 + s];
        float v0 = a_src[sa] + ladst[ta];
        float v1 = a_src[sb] + ladst[tb];
        float v2 = a_src[sc] + ladst[tc];
        float v3 = a_src[sd] + ladst[td];
        v0 = (v0 > 0.0f) ? v0 : 0.2f * v0;
        v1 = (v1 > 0.0f) ? v1 : 0.2f * v1;
        v2 = (v2 > 0.0f) ? v2 : 0.2f * v2;
        v3 = (v3 > 0.0f) ? v3 : 0.2f * v3;
        float w0 = __expf(v0), w1 = __expf(v1);
        float w2 = __expf(v2), w3 = __expf(v3);
        float2 f0a = __half22float2(*(const __half2*)&r0.x);
        float2 f0b = __half22float2(*(const __half2*)&r0.y);
        float2 f1a = __half22float2(*(const __half2*)&r1.x);
        float2 f1b = __half22float2(*(const __half2*)&r1.y);
        float2 f2a = __half22float2(*(const __half2*)&r2.x);
        float2 f2b = __half22float2(*(const __half2*)&r2.y);
        float2 f3a = __half22float2(*(const __half2*)&r3.x);
        float2 f3b = __half22float2(*(const __half2*)&r3.y);
        float* p0 = lacc + ta * HID + s;
        float* p1 = lacc + tb * HID + s;
        float* p2 = lacc + tc * HID + s;
        float* p3 = lacc + td * HID + s;
        lds_fadd(p0 +  0, w0 * f0a.x);
        lds_fadd(p0 + 16, w0 * f0a.y);
        lds_fadd(p0 + 32, w0 * f0b.x);
        lds_fadd(p0 + 48, w0 * f0b.y);
        lds_fadd(p1 +  0, w1 * f1a.x);
        lds_fadd(p1 + 16, w1 * f1a.y);
        lds_fadd(p1 + 32, w1 * f1b.x);
        lds_fadd(p1 + 48, w1 * f1b.y);
        lds_fadd(p2 +  0, w2 * f2a.x);
        lds_fadd(p2 + 16, w2 * f2a.y);
        lds_fadd(p2 + 32, w2 * f2b.x);
        lds_fadd(p2 + 48, w2 * f2b.y);
        lds_fadd(p3 +  0, w3 * f3a.x);
        lds_fadd(p3 + 16, w3 * f3a.y);
        lds_fadd(p3 + 32, w3 * f3b.x);
        lds_fadd(p3 + 48, w3 * f3b.y);
        if (s == 0) {
            lds_fadd(&ldsum[ta], w0);
            lds_fadd(&ldsum[tb], w1);
            lds_fadd(&ldsum[tc], w2);
            lds_fadd(&ldsum[td], w3);
        }
    }
#pragma unroll 1
    for (; j < j1; ++j) {
        int r = rec[beg + j];
        int sa = r >> CBITS, ta = r & (CSZ - 1);
        uint2 r0 = h2[(long long)sa * 16 + s];
        float v0 = a_src[sa] + ladst[ta];
        v0 = (v0 > 0.0f) ? v0 : 0.2f * v0;
        float w0 = __expf(v0);
        float2 f0a = __half22float2(*(const __half2*)&r0.x);
        float2 f0b = __half22float2(*(const __half2*)&r0.y);
        float* p0 = lacc + ta * HID + s;
        lds_fadd(p0 +  0, w0 * f0a.x);
        lds_fadd(p0 + 16, w0 * f0a.y);
        lds_fadd(p0 + 32, w0 * f0b.x);
        lds_fadd(p0 + 48, w0 * f0b.y);
        if (s == 0) lds_fadd(&ldsum[ta], w0);
    }
    __syncthreads();

    // ---- epilogue: out = relu((acc/dsum + bias) @ W_lin + b_lin) ----
    const int lane = t & 63;
    const int gbase = (lane >> 4) << 4;
    float4* out4 = (float4*)out;
#pragma unroll 1
    for (int rnd = 0; rnd < 2; ++rnd) {
        int nloc = rnd * 32 + gid;
        int n = node0 + nloc;
        float4 acc = *(const float4*)(lacc + nloc * HID + 4 * s);
        float inv = 1.0f / (ldsum[nloc] + 1e-16f);
        float4 bsv = bs4[s];
        float4 r;
        r.x = fmaf(acc.x, inv, bsv.x);
        r.y = fmaf(acc.y, inv, bsv.y);
        r.z = fmaf(acc.z, inv, bsv.z);
        r.w = fmaf(acc.w, inv, bsv.w);

        float4 o = bl4[s];
#pragma unroll 4
        for (int ks = 0; ks < 16; ++ks) {
            float rx = __shfl(r.x, gbase + ks, 64);
            float ry = __shfl(r.y, gbase + ks, 64);
            float rz = __shfl(r.z, gbase + ks, 64);
            float rw = __shfl(r.w, gbase + ks, 64);
            o = f4fma(rx, Wl4[(4 * ks + 0) * 16 + s], o);
            o = f4fma(ry, Wl4[(4 * ks + 1) * 16 + s], o);
            o = f4fma(rz, Wl4[(4 * ks + 2) * 16 + s], o);
            o = f4fma(rw, Wl4[(4 * ks + 3) * 16 + s], o);
        }

        if (n < N) {
            float4 res;
            res.x = o.x > 0.0f ? o.x : 0.0f;
            res.y = o.y > 0.0f ? o.y : 0.0f;
            res.z = o.z > 0.0f ? o.z : 0.0f;
            res.w = o.w > 0.0f ? o.w : 0.0f;
            out4[(long long)n * 16 + s] = res;
        }
    }
}

extern "C" void kernel_launch(void* const* d_in, const int* in_sizes, int n_in,
                              void* d_out, int out_size, void* d_ws, size_t ws_size,
                              hipStream_t stream) {
    const float* x       = (const float*)d_in[0];
    const int*   edge    = (const int*)d_in[1];
    const float* W_src   = (const float*)d_in[2];
    const float* W_dst   = (const float*)d_in[3];
    const float* att_src = (const float*)d_in[4];
    const float* att_dst = (const float*)d_in[5];
    const float* bias    = (const float*)d_in[6];
    const float* W_lin   = (const float*)d_in[7];
    const float* b_lin   = (const float*)d_in[8];
    float* out = (float*)d_out;

    const int N = in_sizes[0] / HID;  // 100000
    const int E = in_sizes[1] / 2;    // 1000000
    const int* src = edge;
    const int* tgt = edge + E;
    const int nbc = (N + CSZ - 1) / CSZ;   // 1563 buckets

    // workspace layout
    __half* h_half  = (__half*)d_ws;                      // N*HID halves
    float*  a_src   = (float*)(h_half + (size_t)N * HID); // N
    float*  a_dst   = a_src + N;                          // N
    float*  vdst    = a_dst + N;                          // 64
    int*    gcursor = (int*)(vdst + 64);                  // MAXB
    int*    rec     = gcursor + MAXB;                     // nbc*CAP (~5.2 MB)

    init_kernel<<<8, 256, 0, stream>>>(W_dst, att_dst, vdst, gcursor, nbc);
    mid_kernel<<<PB + MSB, 256, 0, stream>>>(x, W_src, att_src, vdst, h_half,
                                             a_src, a_dst, N,
                                             src, tgt, gcursor, rec, E, nbc);
    gather_kernel<<<nbc, 512, 0, stream>>>(gcursor, rec, h_half, a_src, a_dst,
                                           bias, W_lin, b_lin, out, N);
}

// Round 3
// 162.963 us; speedup vs baseline: 3.2378x; 3.2249x over previous
//
#include <hip/hip_runtime.h>
#include <hip/hip_fp16.h>
#include <math.h>

#define HID 64
#define CBITS 6
#define CSZ 64           // nodes per bucket
#define MAXB 2048        // max buckets supported (N <= 131072)
#define CAP 832          // record slots per bucket (mean 640, sigma ~25 -> +7.6 sigma)
#define CAPH 576         // LDS slots for a 32-node half-bucket (mean 320, sigma ~18 -> +14 sigma)
#define PB 896           // proj blocks in the fused mid kernel
#define MSB 256          // multisplit blocks in the fused mid kernel
#define XSTR 17          // x-tile row stride in float4 (68 floats: +4 pad kills the
                         // 16-way bank conflict of stride-64 broadcast reads)

// ---- float4 helpers -------------------------------------------------------
__device__ __forceinline__ float4 f4fma(float a, const float4 b, float4 c) {
    c.x = fmaf(a, b.x, c.x); c.y = fmaf(a, b.y, c.y);
    c.z = fmaf(a, b.z, c.z); c.w = fmaf(a, b.w, c.w);
    return c;
}

// block 0: vdst[k] = sum_h W_dst[k][h]*att_dst[h]; all blocks: gcursor[i] = i*CAP.
__global__ void init_kernel(const float* __restrict__ W_dst,
                            const float* __restrict__ att_dst,
                            float* __restrict__ vdst,
                            int* __restrict__ gcursor, int nbc) {
    if (blockIdx.x == 0 && threadIdx.x < HID) {
        int k = threadIdx.x;
        float acc = 0.0f;
#pragma unroll 8
        for (int h = 0; h < HID; ++h) acc = fmaf(W_dst[k * HID + h], att_dst[h], acc);
        vdst[k] = acc;
    }
    int stride = gridDim.x * blockDim.x;
    for (int i = blockIdx.x * blockDim.x + threadIdx.x; i < nbc; i += stride)
        gcursor[i] = i * CAP;
}

// Fused mid kernel: blocks [0,PB) run the projection, blocks [PB,PB+MSB) run the
// multisplit. The two phases are data-independent; fusing them lets them overlap
// on the device (both individually underutilize it).
// LDS is a union (25.6 KB) -> 6 blocks/CU, 1152 blocks all co-resident.
//
// proj: h_half = fp16(x @ W_src); a_src = (x@W_src)@att_src; a_dst = x@vdst.
//   R3 (this round) fix: the x-tile in LDS is padded to stride 68 floats and the
//   K-loop reads x as float4 broadcasts. The old stride-64 scalar broadcast
//   xr[k] put all 16 groups on bank k%32 -> 16-way conflict (5.69x, m136) on
//   128 reads/wave-iter -> ~117 us of pure LDS-pipe serialization = the whole
//   mid_kernel cost. Padded stride puts the 4 groups of a wave on disjoint
//   banks; float4 x reads cut LDS instruction count a further ~40%.
//   K-loop unrolled only 4x: full unroll made the compiler hoist LDS loads ->
//   spill to scratch -> ~950 MB phantom HBM traffic (R3/R4 lesson, old session).
// multisplit: bucket i owns rec[i*CAP,(i+1)*CAP). LDS hist -> one global-atomic
//   reservation per bucket per block -> LDS-cursor placement. Record =
//   (src<<6)|(tgt&63). Same-block writes are contiguous ~20 B runs -> no 16x
//   random write-back amplification (R6 lesson, old session).
__global__ void __launch_bounds__(256)
mid_kernel(const float* __restrict__ x,
           const float* __restrict__ W_src,
           const float* __restrict__ att_src,
           const float* __restrict__ vdst,
           __half* __restrict__ h_half,
           float* __restrict__ a_src,
           float* __restrict__ a_dst, int N,
           const int* __restrict__ src, const int* __restrict__ tgt,
           int* __restrict__ gcursor, int* __restrict__ rec, int E, int nbc) {
    __shared__ __align__(16) char smraw[25600];
    const int t = threadIdx.x;

    if (blockIdx.x < PB) {
        // ---------------- projection ----------------
        float4* Ws4  = (float4*)smraw;        // [HID*16]  (16 KB)
        float4* att4 = Ws4 + HID * 16;        // [16]
        float4* vd4  = att4 + 16;             // [16]
        float4* xs4f = vd4 + 16;              // [32*XSTR] padded x tile (8.5 KB)

        for (int i = t; i < HID * 16; i += 256) Ws4[i] = ((const float4*)W_src)[i];
        if (t < 16) {
            att4[t] = ((const float4*)att_src)[t];
            vd4[t]  = ((const float4*)vdst)[t];
        }

        const int g0 = t >> 4;       // node slot 0..15 (second node = g0+16)
        const int s = t & 15;        // float4 chunk within the 64-wide feature dim
        const float4* x4 = (const float4*)x;
        uint2* h2 = (uint2*)h_half;

        for (int base = blockIdx.x * 32; base < N; base += PB * 32) {
            __syncthreads();  // also covers the Ws4 fill on iteration 0
#pragma unroll
            for (int u = 0; u < 2; ++u) {
                int f = t + u * 256;                 // flat float4 id 0..511
                int node = base + (f >> 4);
                xs4f[(f >> 4) * XSTR + (f & 15)] =
                    (node < N) ? x4[(long long)node * 16 + (f & 15)]
                               : make_float4(0, 0, 0, 0);
            }
            __syncthreads();

            const float4* xr0 = xs4f + g0 * XSTR;
            const float4* xr1 = xs4f + (g0 + 16) * XSTR;

            float4 acc0 = make_float4(0, 0, 0, 0);
            float4 acc1 = make_float4(0, 0, 0, 0);
#pragma unroll 4
            for (int kk = 0; kk < 16; ++kk) {
                float4 xv0 = xr0[kk];                // broadcast within group
                float4 xv1 = xr1[kk];
                float4 w0 = Ws4[(4 * kk + 0) * 16 + s];
                float4 w1 = Ws4[(4 * kk + 1) * 16 + s];
                float4 w2 = Ws4[(4 * kk + 2) * 16 + s];
                float4 w3 = Ws4[(4 * kk + 3) * 16 + s];
                acc0 = f4fma(xv0.x, w0, acc0);
                acc1 = f4fma(xv1.x, w0, acc1);
                acc0 = f4fma(xv0.y, w1, acc0);
                acc1 = f4fma(xv1.y, w1, acc1);
                acc0 = f4fma(xv0.z, w2, acc0);
                acc1 = f4fma(xv1.z, w2, acc1);
                acc0 = f4fma(xv0.w, w3, acc0);
                acc1 = f4fma(xv1.w, w3, acc1);
            }

            float4 av = att4[s], qv = vd4[s];
            float p0 = acc0.x * av.x + acc0.y * av.y + acc0.z * av.z + acc0.w * av.w;
            float p1 = acc1.x * av.x + acc1.y * av.y + acc1.z * av.z + acc1.w * av.w;
            float4 xq0 = xr0[s];
            float4 xq1 = xr1[s];
            float q0 = xq0.x * qv.x + xq0.y * qv.y + xq0.z * qv.z + xq0.w * qv.w;
            float q1 = xq1.x * qv.x + xq1.y * qv.y + xq1.z * qv.z + xq1.w * qv.w;
#pragma unroll
            for (int off = 1; off < 16; off <<= 1) {
                p0 += __shfl_xor(p0, off, 64);
                p1 += __shfl_xor(p1, off, 64);
                q0 += __shfl_xor(q0, off, 64);
                q1 += __shfl_xor(q1, off, 64);
            }

            int n0 = base + g0, n1 = base + g0 + 16;
            if (n0 < N) {
                __half2 lo = __float22half2_rn(make_float2(acc0.x, acc0.y));
                __half2 hi = __float22half2_rn(make_float2(acc0.z, acc0.w));
                uint2 pk; pk.x = *(unsigned*)&lo; pk.y = *(unsigned*)&hi;
                h2[(long long)n0 * 16 + s] = pk;
                if (s == 0) { a_src[n0] = p0; a_dst[n0] = q0; }
            }
            if (n1 < N) {
                __half2 lo = __float22half2_rn(make_float2(acc1.x, acc1.y));
                __half2 hi = __float22half2_rn(make_float2(acc1.z, acc1.w));
                uint2 pk; pk.x = *(unsigned*)&lo; pk.y = *(unsigned*)&hi;
                h2[(long long)n1 * 16 + s] = pk;
                if (s == 0) { a_src[n1] = p1; a_dst[n1] = q1; }
            }
        }
    } else {
        // ---------------- multisplit ----------------
        int* lh = (int*)smraw;                // [nbc]
        const int bid = blockIdx.x - PB;

        for (int i = t; i < nbc; i += 256) lh[i] = 0;
        __syncthreads();
        int chunk = (E + MSB - 1) / MSB;
        int e0 = bid * chunk;
        int e1 = min(E, e0 + chunk);
        for (int e = e0 + t; e < e1; e += 256)
            atomicAdd(&lh[tgt[e] >> CBITS], 1);
        __syncthreads();
        // reserve: lh[i] becomes this block's base slot for bucket i
        for (int i = t; i < nbc; i += 256)
            if (lh[i]) lh[i] = atomicAdd(&gcursor[i], lh[i]);
        __syncthreads();
        for (int e = e0 + t; e < e1; e += 256) {
            int s = src[e], tg = tgt[e];
            int bi = tg >> CBITS;
            int pos = atomicAdd(&lh[bi], 1);           // LDS atomic (~50cy, not ~500)
            if (pos < (bi + 1) * CAP)                  // overflow guard
                rec[pos] = (s << CBITS) | (tg & (CSZ - 1));
        }
    }
}

// fused fine-sort + gather + output GEMM. TWO blocks per 64-node bucket: block
// (bk,half) extracts only its 32 targets' records (records re-read from global,
// L2-hot), counting-sorts them in LDS (~19.5 KB total -> 8 blocks/CU, grid 2x),
// then each wave processes 8 nodes (4 at a time, 16 lanes x 4 halves each):
// w = exp(LeakyReLU(a_src[s]+a_dst[n])), acc += w*h_row;
// out = relu((acc/dsum+bias)@W_lin+b_lin). Logits bounded -> no max-subtraction.
__global__ void __launch_bounds__(256)
sort_gather_kernel(const int* __restrict__ gcursor, const int* __restrict__ rec,
                   const __half* __restrict__ h_half,
                   const float* __restrict__ a_src, const float* __restrict__ a_dst,
                   const float* __restrict__ bias,
                   const float* __restrict__ W_lin, const float* __restrict__ b_lin,
                   float* __restrict__ out, int N) {
    __shared__ float4 Wl4[HID * 16];   // 16 KB
    __shared__ float4 bs4[16], bl4[16];
    __shared__ int ssort[CAPH];        // 2.25 KB
    __shared__ int hist[32];
    __shared__ int loff[33];
    __shared__ int cur[32];
    __shared__ int sd[32];

    const int t = threadIdx.x;
    for (int i = t; i < HID * 16; i += 256) Wl4[i] = ((const float4*)W_lin)[i];
    if (t < 16) {
        bs4[t] = ((const float4*)bias)[t];
        bl4[t] = ((const float4*)b_lin)[t];
    }

    const int bk = blockIdx.x >> 1;
    const int half = blockIdx.x & 1;
    const int node0 = (bk << CBITS) + half * 32;
    const int nn = min(32, N - node0);          // may be <= 0 for the final half
    const int beg = bk * CAP;
    int cnt = gcursor[bk] - beg;
    if (cnt > CAP) cnt = CAP;

    if (t < 32) hist[t] = 0;
    __syncthreads();
    for (int j = t; j < cnt; j += 256) {
        int tl = rec[beg + j] & (CSZ - 1);
        if ((tl >> 5) == half) atomicAdd(&hist[tl & 31], 1);
    }
    __syncthreads();
    if (t < 32) sd[t] = hist[t];
    __syncthreads();
    for (int off = 1; off < 32; off <<= 1) {
        int v = (t < 32 && t >= off) ? sd[t - off] : 0;
        __syncthreads();
        if (t < 32) sd[t] += v;
        __syncthreads();
    }
    if (t < 32) {
        int e = sd[t] - hist[t];
        loff[t] = e; cur[t] = e;
        if (t == 31) loff[32] = min(sd[31], CAPH);
    }
    __syncthreads();
    for (int j = t; j < cnt; j += 256) {
        int r = rec[beg + j];
        int tl = r & (CSZ - 1);
        if ((tl >> 5) == half) {
            int pos = atomicAdd(&cur[tl & 31], 1);
            if (pos < CAPH) ssort[pos] = r >> CBITS;
        }
    }
    __syncthreads();

    // gather + output GEMM
    const int lane = t & 63;
    const int w = t >> 6;
    const int g = lane >> 4;
    const int s = lane & 15;
    const int gbase = g << 4;
    const uint2* h2 = (const uint2*)h_half;
    float4* out4 = (float4*)out;

#pragma unroll 1
    for (int r2 = 0; r2 < 2; ++r2) {
        int nloc = w * 8 + r2 * 4 + g;          // 0..31
        int n = node0 + nloc;
        bool act = (nloc < nn);
        float adn = act ? a_dst[n] : 0.0f;
        int jb = min(loff[nloc], CAPH);
        int je = min(loff[nloc + 1], CAPH);

        float4 acc = make_float4(0, 0, 0, 0);
        float dsum = 0.0f;
        int j = jb;
        for (; j + 4 <= je; j += 4) {
            int s0 = ssort[j], s1 = ssort[j + 1], s2 = ssort[j + 2], s3 = ssort[j + 3];
            uint2 r0 = h2[(long long)s0 * 16 + s];
            uint2 r1 = h2[(long long)s1 * 16 + s];
            uint2 r2v = h2[(long long)s2 * 16 + s];
            uint2 r3 = h2[(long long)s3 * 16 + s];
            float v0 = a_src[s0] + adn, v1 = a_src[s1] + adn;
            float v2 = a_src[s2] + adn, v3 = a_src[s3] + adn;
            v0 = (v0 > 0.0f) ? v0 : 0.2f * v0;
            v1 = (v1 > 0.0f) ? v1 : 0.2f * v1;
            v2 = (v2 > 0.0f) ? v2 : 0.2f * v2;
            v3 = (v3 > 0.0f) ? v3 : 0.2f * v3;
            float w0 = __expf(v0), w1 = __expf(v1);
            float w2 = __expf(v2), w3 = __expf(v3);
            dsum += (w0 + w1) + (w2 + w3);
            float2 f0a = __half22float2(*(const __half2*)&r0.x);
            float2 f0b = __half22float2(*(const __half2*)&r0.y);
            float2 f1a = __half22float2(*(const __half2*)&r1.x);
            float2 f1b = __half22float2(*(const __half2*)&r1.y);
            float2 f2a = __half22float2(*(const __half2*)&r2v.x);
            float2 f2b = __half22float2(*(const __half2*)&r2v.y);
            float2 f3a = __half22float2(*(const __half2*)&r3.x);
            float2 f3b = __half22float2(*(const __half2*)&r3.y);
            acc.x = fmaf(w0, f0a.x, fmaf(w1, f1a.x, fmaf(w2, f2a.x, fmaf(w3, f3a.x, acc.x))));
            acc.y = fmaf(w0, f0a.y, fmaf(w1, f1a.y, fmaf(w2, f2a.y, fmaf(w3, f3a.y, acc.y))));
            acc.z = fmaf(w0, f0b.x, fmaf(w1, f1b.x, fmaf(w2, f2b.x, fmaf(w3, f3b.x, acc.z))));
            acc.w = fmaf(w0, f0b.y, fmaf(w1, f1b.y, fmaf(w2, f2b.y, fmaf(w3, f3b.y, acc.w))));
        }
        for (; j < je; ++j) {
            int s0 = ssort[j];
            uint2 r0 = h2[(long long)s0 * 16 + s];
            float v0 = a_src[s0] + adn;
            v0 = (v0 > 0.0f) ? v0 : 0.2f * v0;
            float w0 = __expf(v0);
            dsum += w0;
            float2 f0a = __half22float2(*(const __half2*)&r0.x);
            float2 f0b = __half22float2(*(const __half2*)&r0.y);
            acc.x = fmaf(w0, f0a.x, acc.x);
            acc.y = fmaf(w0, f0a.y, acc.y);
            acc.z = fmaf(w0, f0b.x, acc.z);
            acc.w = fmaf(w0, f0b.y, acc.w);
        }

        float inv = 1.0f / (dsum + 1e-16f);
        float4 bsv = bs4[s];
        float4 r;
        r.x = fmaf(acc.x, inv, bsv.x);
        r.y = fmaf(acc.y, inv, bsv.y);
        r.z = fmaf(acc.z, inv, bsv.z);
        r.w = fmaf(acc.w, inv, bsv.w);

        float4 o = bl4[s];
#pragma unroll 4
        for (int ks = 0; ks < 16; ++ks) {
            float rx = __shfl(r.x, gbase + ks, 64);
            float ry = __shfl(r.y, gbase + ks, 64);
            float rz = __shfl(r.z, gbase + ks, 64);
            float rw = __shfl(r.w, gbase + ks, 64);
            o = f4fma(rx, Wl4[(4 * ks + 0) * 16 + s], o);
            o = f4fma(ry, Wl4[(4 * ks + 1) * 16 + s], o);
            o = f4fma(rz, Wl4[(4 * ks + 2) * 16 + s], o);
            o = f4fma(rw, Wl4[(4 * ks + 3) * 16 + s], o);
        }

        if (act) {
            float4 res;
            res.x = o.x > 0.0f ? o.x : 0.0f;
            res.y = o.y > 0.0f ? o.y : 0.0f;
            res.z = o.z > 0.0f ? o.z : 0.0f;
            res.w = o.w > 0.0f ? o.w : 0.0f;
            out4[(long long)n * 16 + s] = res;
        }
    }
}

extern "C" void kernel_launch(void* const* d_in, const int* in_sizes, int n_in,
                              void* d_out, int out_size, void* d_ws, size_t ws_size,
                              hipStream_t stream) {
    const float* x       = (const float*)d_in[0];
    const int*   edge    = (const int*)d_in[1];
    const float* W_src   = (const float*)d_in[2];
    const float* W_dst   = (const float*)d_in[3];
    const float* att_src = (const float*)d_in[4];
    const float* att_dst = (const float*)d_in[5];
    const float* bias    = (const float*)d_in[6];
    const float* W_lin   = (const float*)d_in[7];
    const float* b_lin   = (const float*)d_in[8];
    float* out = (float*)d_out;

    const int N = in_sizes[0] / HID;  // 100000
    const int E = in_sizes[1] / 2;    // 1000000
    const int* src = edge;
    const int* tgt = edge + E;
    const int nbc = (N + CSZ - 1) / CSZ;   // 1563 buckets

    // workspace layout
    __half* h_half  = (__half*)d_ws;                      // N*HID halves
    float*  a_src   = (float*)(h_half + (size_t)N * HID); // N
    float*  a_dst   = a_src + N;                          // N
    float*  vdst    = a_dst + N;                          // 64
    int*    gcursor = (int*)(vdst + 64);                  // MAXB
    int*    rec     = gcursor + MAXB;                     // nbc*CAP (~5.2 MB)

    init_kernel<<<8, 256, 0, stream>>>(W_dst, att_dst, vdst, gcursor, nbc);
    mid_kernel<<<PB + MSB, 256, 0, stream>>>(x, W_src, att_src, vdst, h_half,
                                             a_src, a_dst, N,
                                             src, tgt, gcursor, rec, E, nbc);
    sort_gather_kernel<<<nbc * 2, 256, 0, stream>>>(gcursor, rec, h_half, a_src, a_dst,
                                                    bias, W_lin, b_lin, out, N);
}